// Round 13
// baseline (301.243 us; speedup 1.0000x reference)
//
#include <hip/hip_runtime.h>
#include <hip/hip_bf16.h>
#include <cstdint>
#include <cstddef>

#define NE 8
#define N_TOK 8192
#define D_EMB 1024
#define D_FFN 2048

#define BM 256
#define BN 256
#define BK 32

typedef __attribute__((ext_vector_type(8))) short short8;
typedef __attribute__((ext_vector_type(4))) float f32x4;

__device__ __forceinline__ unsigned short f2bf(float f) {
  union { float f; unsigned int u; } c; c.f = f;
  unsigned int u = c.u;
  unsigned int r = u + 0x7FFFu + ((u >> 16) & 1u);
  return (unsigned short)(r >> 16);
}

__device__ __forceinline__ float bf2f(unsigned short u) {
  union { unsigned int u; float f; } c; c.u = ((unsigned int)u) << 16;
  return c.f;
}

// gelu, tanh-form as sigmoid: x*sig(2c(x+0.044715x^3)); |delta| <= 3e-3 on h,
// ~1.4e-3 after W2 diffusion. ~8 VALU ops vs erff's ~25.
__device__ __forceinline__ float gelu_f(float x) {
  float u = x * x * x * 0.044715f + x;
  float t = __expf(-1.5957691216057308f * u);
  return x * __builtin_amdgcn_rcpf(1.f + t);
}

__device__ __forceinline__ void gll16(const void* g, void* l) {
  __builtin_amdgcn_global_load_lds((const __attribute__((address_space(1))) void*)g,
                                   (__attribute__((address_space(3))) void*)l, 16, 0, 0);
}

#define SB() __builtin_amdgcn_sched_barrier(0)
#define VW(N) { asm volatile("s_waitcnt vmcnt(" #N ")" ::: "memory"); SB(); }
#define BAR() { SB(); __builtin_amdgcn_s_barrier(); SB(); }
#define LKW() { asm volatile("s_waitcnt lgkmcnt(0)" ::: "memory"); SB(); }

// ---- router: fp32 logits, top-2 + renorm gates; fused x->bf16 convert ------
__global__ __launch_bounds__(256) void router_k(const float* __restrict__ x,
                                                const float* __restrict__ rw,
                                                int* __restrict__ ti,
                                                float* __restrict__ tg,
                                                ushort* __restrict__ xb) {
  int w = threadIdx.x >> 6, lane = threadIdx.x & 63;
  int n = blockIdx.x * 4 + w;
  const float4* x4 = (const float4*)(x + (size_t)n * D_EMB);
  ushort4* xb4 = (ushort4*)(xb + (size_t)n * D_EMB);
  const float4* r4 = (const float4*)rw;
  float acc[NE];
#pragma unroll
  for (int e = 0; e < NE; ++e) acc[e] = 0.f;
#pragma unroll
  for (int c = 0; c < 4; ++c) {
    float4 xv = x4[c * 64 + lane];
    ushort4 o;
    o.x = f2bf(xv.x); o.y = f2bf(xv.y); o.z = f2bf(xv.z); o.w = f2bf(xv.w);
    xb4[c * 64 + lane] = o;
#pragma unroll
    for (int e = 0; e < NE; ++e) {
      float4 wv = r4[e * 256 + c * 64 + lane];
      acc[e] += xv.x * wv.x + xv.y * wv.y + xv.z * wv.z + xv.w * wv.w;
    }
  }
#pragma unroll
  for (int e = 0; e < NE; ++e) {
    float v = acc[e];
#pragma unroll
    for (int off = 32; off >= 1; off >>= 1) v += __shfl_xor(v, off);
    acc[e] = v;
  }
  if (lane == 0) {
    int e0 = 0; float v0 = acc[0];
#pragma unroll
    for (int e = 1; e < NE; ++e) if (acc[e] > v0) { v0 = acc[e]; e0 = e; }
    int e1 = -1; float v1 = -1e30f;
#pragma unroll
    for (int e = 0; e < NE; ++e) if (e != e0 && acc[e] > v1) { v1 = acc[e]; e1 = e; }
    float p1 = expf(v1 - v0);          // p(top2)/p(top1)
    float g0 = 1.f / (1.f + p1);
    float g1 = p1 * g0;
    ti[2 * n] = e0; ti[2 * n + 1] = e1;
    tg[2 * n] = g0; tg[2 * n + 1] = g1;
  }
}

// ---- prep: fused {W1-transpose, W2-per-expert-transpose, hist} -------------
__global__ __launch_bounds__(256) void prep_k(const float* __restrict__ w1,
                                              const float* __restrict__ w2,
                                              const int* __restrict__ ti,
                                              ushort* __restrict__ w1t,
                                              ushort* __restrict__ w2te,
                                              int* __restrict__ counts) {
  int b = blockIdx.x;
  if (b >= 32768) {                       // ---- hist ----
    __shared__ int lc[NE];
    if (threadIdx.x < NE) lc[threadIdx.x] = 0;
    __syncthreads();
    int s = (b - 32768) * 512 + threadIdx.x;
    atomicAdd(&lc[ti[s]], 1);
    atomicAdd(&lc[ti[s + 256]], 1);
    __syncthreads();
    if (threadIdx.x < NE) atomicAdd(&counts[threadIdx.x], lc[threadIdx.x]);
    return;
  }
  __shared__ ushort t[32][33];
  int rl = threadIdx.x >> 3, q = threadIdx.x & 7;
  if (b < 16384) {                        // ---- W1 transpose ----
    int bx = b & 511, by = b >> 9;
    const int C = NE * D_FFN;
    float4 v = *(const float4*)&w1[(size_t)(by * 32 + rl) * C + bx * 32 + q * 4];
    t[rl][q * 4 + 0] = f2bf(v.x);
    t[rl][q * 4 + 1] = f2bf(v.y);
    t[rl][q * 4 + 2] = f2bf(v.z);
    t[rl][q * 4 + 3] = f2bf(v.w);
    __syncthreads();
    ushort4 o;
    o.x = t[q * 4 + 0][rl];
    o.y = t[q * 4 + 1][rl];
    o.z = t[q * 4 + 2][rl];
    o.w = t[q * 4 + 3][rl];
    *(ushort4*)&w1t[(size_t)(bx * 32 + rl) * D_EMB + by * 32 + q * 4] = o;
  } else {                                // ---- W2 per-expert transpose ----
    int b2 = b - 16384;
    int bx = b2 & 31, by = b2 >> 5;
    float4 v = *(const float4*)&w2[(size_t)(by * 32 + rl) * D_EMB + bx * 32 + q * 4];
    t[rl][q * 4 + 0] = f2bf(v.x);
    t[rl][q * 4 + 1] = f2bf(v.y);
    t[rl][q * 4 + 2] = f2bf(v.z);
    t[rl][q * 4 + 3] = f2bf(v.w);
    __syncthreads();
    int e = by >> 6;
    int f0 = (by & 63) * 32;
    size_t eoff = (size_t)e * (D_EMB * D_FFN);
    ushort4 o;
    o.x = t[q * 4 + 0][rl];
    o.y = t[q * 4 + 1][rl];
    o.z = t[q * 4 + 2][rl];
    o.w = t[q * 4 + 3][rl];
    *(ushort4*)&w2te[eoff + (size_t)(bx * 32 + rl) * D_FFN + f0 + q * 4] = o;
  }
}

__global__ void prefix_k(const int* __restrict__ counts, int* __restrict__ bases,
                         int* __restrict__ cursor) {
  if (threadIdx.x == 0) {
    int s = 0;
    for (int e = 0; e < NE; ++e) { bases[e] = s; cursor[e] = s; s += counts[e]; }
  }
}

// ---- scatter: two-phase; tokS[pos] = s (= token*2 + slot-index) ------------
__global__ __launch_bounds__(256) void scatter_k(const int* __restrict__ ti,
                                                 const float* __restrict__ tg,
                                                 int* __restrict__ cursor,
                                                 int* __restrict__ tokS,
                                                 float* __restrict__ gate) {
  __shared__ int lc[NE], lb[NE];
  if (threadIdx.x < NE) lc[threadIdx.x] = 0;
  __syncthreads();
  int s = blockIdx.x * 256 + threadIdx.x;
  int e = ti[s];
  float g = tg[s];
  int loc = atomicAdd(&lc[e], 1);
  __syncthreads();
  if (threadIdx.x < NE) lb[threadIdx.x] = atomicAdd(&cursor[threadIdx.x], lc[threadIdx.x]);
  __syncthreads();
  int pos = lb[e] + loc;
  tokS[pos] = s;
  gate[pos] = g;
}

// ===== 256x256 / BK=32 grouped GEMM, 8 waves, dbuf + counted vmcnt(4) =======
// Proven 2-phase KLOOP discipline (R7), tile scaled 128->256 (the one
// untested parameter cell; guide: +10% at same phase). Stage = 2 passes x
// (A,B) = 4 gll16/thread -> vmcnt(4) ledger IDENTICAL to the 128 template.
// Slot swizzle phys = slot ^ ((row>>1)&3), both-sides (pre-swizzled global
// col ssw + swizzled read rsw); formulas carry over (row = tid>>2; f*16 row
// offsets are 0 mod 4). Wave (wm,wn) = 2Mx4N owns 128x64; acc[8][4].
// Epilogue: LDS-staged vectorized stores (per-wave 16x72 strip in dead Al).

#define STG(BUF)                                                           \
  { _Pragma("unroll") for (int p_ = 0; p_ < 2; ++p_) {                     \
      gll16(aptr[p_], &Al[BUF][p_ * 4096 + w * 512]);                      \
      gll16(bptr[p_], &Bl[BUF][p_ * 4096 + w * 512]);                      \
      aptr[p_] += BK; bptr[p_] += BK;                                      \
    } }

#define CMP(BUF)                                                           \
  { short8 a[8], b[4];                                                     \
    _Pragma("unroll") for (int i_ = 0; i_ < 8; ++i_)                       \
      a[i_] = *(const short8*)&Al[BUF][arow + i_ * 16 * BK];               \
    _Pragma("unroll") for (int j_ = 0; j_ < 4; ++j_)                       \
      b[j_] = *(const short8*)&Bl[BUF][brow + j_ * 16 * BK];               \
    _Pragma("unroll") for (int i_ = 0; i_ < 8; ++i_)                       \
      _Pragma("unroll") for (int j_ = 0; j_ < 4; ++j_)                     \
        acc[i_][j_] = __builtin_amdgcn_mfma_f32_16x16x32_bf16(a[i_], b[j_], acc[i_][j_], 0, 0, 0); \
  }

#define KLOOP(NT)                                                          \
  STG(0);                                                                  \
  for (int ks = 0; ks < (NT) - 2; ks += 2) {                               \
    STG(1); VW(4); BAR(); CMP(0); BAR();                                   \
    STG(0); VW(4); BAR(); CMP(1); BAR();                                   \
  }                                                                        \
  STG(1); VW(4); BAR(); CMP(0); BAR();                                     \
  VW(0); BAR(); CMP(1);

// ---------------- grouped GEMM1: h = gelu(x @ W1_e), gathered rows ----------
__global__ __launch_bounds__(512, 2) void gemm1_k(const ushort* __restrict__ xb,
                                                  const ushort* __restrict__ w1t,
                                                  const int* __restrict__ counts,
                                                  const int* __restrict__ bases,
                                                  const int* __restrict__ tokS,
                                                  ushort* __restrict__ h) {
  int bid = (int)blockIdx.x;
  bid = (bid & 7) * 128 + (bid >> 3);   // XCD-contiguous: 1 expert/XCD
  int e = bid >> 7;                     // 16 mt * 8 nt per expert (cap 4096)
  int rem = bid & 127;
  int mt = rem >> 3, nt = rem & 7;
  int count = counts[e];
  if (mt * BM >= count) return;
  int base = bases[e];

  __shared__ ushort Al[2][BM * BK];     // 2 x 16KB
  __shared__ ushort Bl[2][BN * BK];     // 2 x 16KB

  int tid = threadIdx.x;
  int w = tid >> 6, lane = tid & 63;
  const int l15 = lane & 15;

  // staging: thread covers LDS row tid>>2 (+128/pass), phys slot tid&3;
  // pre-swizzled source col: logical = (tid&3) ^ ((tid>>3)&3)
  const int ssw = (((tid & 3) ^ ((tid >> 3) & 3))) * 8;

  const ushort* aptr[2]; const ushort* bptr[2];
#pragma unroll
  for (int p = 0; p < 2; ++p) {
    int R = p * 128 + (tid >> 2);
    int pr = min(base + mt * BM + R, base + count - 1);
    int t = tokS[pr] >> 1;
    aptr[p] = xb + (size_t)t * D_EMB + ssw;
    int cB = e * D_FFN + nt * BN + R;
    bptr[p] = w1t + (size_t)cB * D_EMB + ssw;
  }

  f32x4 zero = {0.f, 0.f, 0.f, 0.f};
  f32x4 acc[8][4];
#pragma unroll
  for (int i = 0; i < 8; ++i)
#pragma unroll
    for (int j = 0; j < 4; ++j) acc[i][j] = zero;

  int wm = w >> 2, wn = w & 3;
  const int rsw = ((lane >> 4) ^ ((l15 >> 1) & 3)) * 8;
  const int arow = (wm * 128 + l15) * BK + rsw;
  const int brow = (wn * 64 + l15) * BK + rsw;

  KLOOP(D_EMB / BK);   // 32 tiles

  // ---- LDS-staged vectorized epilogue ----
  __syncthreads();                      // all waves done reading Al/Bl
  ushort* ep = &Al[0][0] + w * 1152;    // 16x72 strip per wave
  int r0 = mt * BM + wm * 128, c0 = nt * BN + wn * 64;
#pragma unroll
  for (int i = 0; i < 8; ++i) {
#pragma unroll
    for (int j = 0; j < 4; ++j)
#pragma unroll
      for (int q = 0; q < 4; ++q)
        ep[((lane >> 4) * 4 + q) * 72 + j * 16 + l15] = f2bf(gelu_f(acc[i][j][q]));
    LKW();                              // intra-wave write->read (DS in-order)
#pragma unroll
    for (int rd = 0; rd < 2; ++rd) {
      int sr = (lane >> 3) + rd * 8;
      int sc = (lane & 7) * 8;
      short8 v = *(const short8*)&ep[sr * 72 + sc];
      int row = r0 + i * 16 + sr;
      if (row < count)
        *(short8*)&h[(size_t)(base + row) * D_FFN + c0 + sc] = v;
    }
    LKW();                              // reads done before next-iter writes
  }
}

// -- grouped GEMM2: y2[tok*2+k] = gate * (h @ W2_e), token-major, bf16 -------
__global__ __launch_bounds__(512, 2) void gemm2_k(const ushort* __restrict__ h,
                                                  const ushort* __restrict__ w2te,
                                                  const int* __restrict__ counts,
                                                  const int* __restrict__ bases,
                                                  const int* __restrict__ tokS,
                                                  const float* __restrict__ gate,
                                                  ushort* __restrict__ y2) {
  int bid = (int)blockIdx.x;
  bid = (bid & 7) * 64 + (bid >> 3);    // XCD-contiguous: 1 expert/XCD
  int e = bid >> 6;                     // 16 mt * 4 nt per expert (cap 4096)
  int rem = bid & 63;
  int mt = rem >> 2, nt = rem & 3;
  int count = counts[e];
  if (mt * BM >= count) return;
  int base = bases[e];

  __shared__ ushort Al[2][BM * BK];
  __shared__ ushort Bl[2][BN * BK];

  int tid = threadIdx.x;
  int w = tid >> 6, lane = tid & 63;
  const int l15 = lane & 15;

  const int ssw = (((tid & 3) ^ ((tid >> 3) & 3))) * 8;

  const ushort* aptr[2]; const ushort* bptr[2];
#pragma unroll
  for (int p = 0; p < 2; ++p) {
    int R = p * 128 + (tid >> 2);
    int pr = min(base + mt * BM + R, base + count - 1);
    aptr[p] = h + (size_t)pr * D_FFN + ssw;
    int d = nt * BN + R;                // output column (embedding dim)
    bptr[p] = w2te + (size_t)e * (D_EMB * D_FFN) + (size_t)d * D_FFN + ssw;
  }

  f32x4 zero = {0.f, 0.f, 0.f, 0.f};
  f32x4 acc[8][4];
#pragma unroll
  for (int i = 0; i < 8; ++i)
#pragma unroll
    for (int j = 0; j < 4; ++j) acc[i][j] = zero;

  int wm = w >> 2, wn = w & 3;
  const int rsw = ((lane >> 4) ^ ((l15 >> 1) & 3)) * 8;
  const int arow = (wm * 128 + l15) * BK + rsw;
  const int brow = (wn * 64 + l15) * BK + rsw;

  KLOOP(D_FFN / BK);   // 64 tiles

  // ---- LDS-staged vectorized epilogue (gate applied pre-stage) ----
  __syncthreads();
  ushort* ep = &Al[0][0] + w * 1152;
  int r0 = mt * BM + wm * 128, c0 = nt * BN + wn * 64;
#pragma unroll
  for (int i = 0; i < 8; ++i) {
#pragma unroll
    for (int q = 0; q < 4; ++q) {
      int row = r0 + i * 16 + (lane >> 4) * 4 + q;
      int pr = min(base + row, base + count - 1);   // clamp: no OOB gate read
      float g = gate[pr];
#pragma unroll
      for (int j = 0; j < 4; ++j)
        ep[((lane >> 4) * 4 + q) * 72 + j * 16 + l15] = f2bf(g * acc[i][j][q]);
    }
    LKW();
#pragma unroll
    for (int rd = 0; rd < 2; ++rd) {
      int sr = (lane >> 3) + rd * 8;
      int sc = (lane & 7) * 8;
      short8 v = *(const short8*)&ep[sr * 72 + sc];
      int row = r0 + i * 16 + sr;
      if (row < count) {
        int pr = base + row;
        *(short8*)&y2[(size_t)tokS[pr] * D_EMB + c0 + sc] = v;  // token-major
      }
    }
    LKW();
  }
}

// ---- combine: out[n] = y2[2n] + y2[2n+1] (streaming, gates pre-applied) ----
__global__ __launch_bounds__(256) void combine_k(const ushort* __restrict__ y2,
                                                 float* __restrict__ out) {
  int n = blockIdx.x;
  const ushort4* r0 = (const ushort4*)(y2 + (size_t)(2 * n) * D_EMB);
  const ushort4* r1 = (const ushort4*)(y2 + (size_t)(2 * n + 1) * D_EMB);
  float4* o = (float4*)(out + (size_t)n * D_EMB);
  int i = threadIdx.x;
  ushort4 a = r0[i], b = r1[i];
  float4 v;
  v.x = bf2f(a.x) + bf2f(b.x);
  v.y = bf2f(a.y) + bf2f(b.y);
  v.z = bf2f(a.z) + bf2f(b.z);
  v.w = bf2f(a.w) + bf2f(b.w);
  o[i] = v;
}

extern "C" void kernel_launch(void* const* d_in, const int* in_sizes, int n_in,
                              void* d_out, int out_size, void* d_ws, size_t ws_size,
                              hipStream_t stream) {
  const float* x  = (const float*)d_in[0];
  const float* rw = (const float*)d_in[1];
  const float* w1 = (const float*)d_in[2];
  const float* w2 = (const float*)d_in[3];
  float* out = (float*)d_out;

  char* ws = (char*)d_ws;
  size_t off = 0;
  auto alloc = [&](size_t bytes) {
    void* p = ws + off;
    off = (off + bytes + 255) & ~(size_t)255;
    return p;
  };
  int*    counts = (int*)alloc(32);
  int*    bases  = (int*)alloc(32);
  int*    cursor = (int*)alloc(32);
  int*    ti     = (int*)alloc((size_t)N_TOK * 2 * sizeof(int));
  float*  tg     = (float*)alloc((size_t)N_TOK * 2 * sizeof(float));
  int*    tokS   = (int*)alloc((size_t)N_TOK * 2 * sizeof(int));
  float*  gate   = (float*)alloc((size_t)N_TOK * 2 * sizeof(float));
  ushort* xb     = (ushort*)alloc((size_t)N_TOK * D_EMB * 2);
  ushort* w1t    = (ushort*)alloc((size_t)D_EMB * NE * D_FFN * 2);
  ushort* w2te   = (ushort*)alloc((size_t)D_EMB * NE * D_FFN * 2);
  ushort* hbuf   = (ushort*)alloc((size_t)N_TOK * 2 * D_FFN * 2);
  ushort* ybuf   = (ushort*)alloc((size_t)N_TOK * 2 * D_EMB * 2);
  (void)ws_size; (void)in_sizes; (void)n_in; (void)out_size;

  hipMemsetAsync(counts, 0, 32, stream);

  router_k<<<N_TOK / 4, 256, 0, stream>>>(x, rw, ti, tg, xb);
  prep_k<<<32800, 256, 0, stream>>>(w1, w2, ti, w1t, w2te, counts);
  prefix_k<<<1, 64, 0, stream>>>(counts, bases, cursor);
  scatter_k<<<N_TOK * 2 / 256, 256, 0, stream>>>(ti, tg, cursor, tokS, gate);
  gemm1_k<<<NE * 16 * 8, 512, 0, stream>>>(xb, w1t, counts, bases, tokS, hbuf);
  gemm2_k<<<NE * 16 * 4, 512, 0, stream>>>(hbuf, w2te, counts, bases, tokS, gate, ybuf);
  combine_k<<<N_TOK, 256, 0, stream>>>(ybuf, out);
}

// Round 14
// 280.019 us; speedup vs baseline: 1.0758x; 1.0758x over previous
//
#include <hip/hip_runtime.h>
#include <hip/hip_bf16.h>
#include <cstdint>
#include <cstddef>

#define NE 8
#define N_TOK 8192
#define D_EMB 1024
#define D_FFN 2048

#define BM 128
#define BN 128
#define BK 32

typedef __attribute__((ext_vector_type(8))) short short8;
typedef __attribute__((ext_vector_type(4))) float f32x4;

__device__ __forceinline__ unsigned short f2bf(float f) {
  union { float f; unsigned int u; } c; c.f = f;
  unsigned int u = c.u;
  unsigned int r = u + 0x7FFFu + ((u >> 16) & 1u);
  return (unsigned short)(r >> 16);
}

__device__ __forceinline__ float bf2f(unsigned short u) {
  union { unsigned int u; float f; } c; c.u = ((unsigned int)u) << 16;
  return c.f;
}

// gelu, tanh-form as sigmoid: x*sig(2c(x+0.044715x^3)); |delta| <= 3e-3 on h,
// ~1.4e-3 after W2 diffusion. ~8 VALU ops vs erff's ~25.
__device__ __forceinline__ float gelu_f(float x) {
  float u = x * x * x * 0.044715f + x;
  float t = __expf(-1.5957691216057308f * u);
  return x * __builtin_amdgcn_rcpf(1.f + t);
}

__device__ __forceinline__ void gll16(const void* g, void* l) {
  __builtin_amdgcn_global_load_lds((const __attribute__((address_space(1))) void*)g,
                                   (__attribute__((address_space(3))) void*)l, 16, 0, 0);
}

#define SB() __builtin_amdgcn_sched_barrier(0)
#define VW(N) { asm volatile("s_waitcnt vmcnt(" #N ")" ::: "memory"); SB(); }
#define BAR() { SB(); __builtin_amdgcn_s_barrier(); SB(); }
#define LKW() { asm volatile("s_waitcnt lgkmcnt(0)" ::: "memory"); SB(); }

// ---- prep: fused {W1-transpose, W2-per-expert-transpose, ROUTER} -----------
// All partitions mutually independent; router's 48MB rides the transposes'
// 192MB BW window instead of a serial pre-launch. Block 0 also zeroes counts
// (hist runs in a LATER launch -> no ordering hazard). Grid partition:
//   [0, 16384)        : W1 [D_EMB][NE*D_FFN] fp32 -> w1t [NE*D_FFN][D_EMB] bf16
//   [16384, 32768)    : W2 [NE*D_FFN][D_EMB] fp32 -> w2te [NE][D_EMB][D_FFN] bf16
//   [32768, 34816)    : router (4 tokens/block): fp32 logits, top-2 + renorm
//                       gates, fused x->bf16 convert
__global__ __launch_bounds__(256) void prep_k(const float* __restrict__ w1,
                                              const float* __restrict__ w2,
                                              const float* __restrict__ x,
                                              const float* __restrict__ rw,
                                              ushort* __restrict__ w1t,
                                              ushort* __restrict__ w2te,
                                              ushort* __restrict__ xb,
                                              int* __restrict__ ti,
                                              float* __restrict__ tg,
                                              int* __restrict__ counts) {
  int b = blockIdx.x;
  if (b == 0 && threadIdx.x < NE) counts[threadIdx.x] = 0;
  if (b >= 32768) {                       // ---- router ----
    int w = threadIdx.x >> 6, lane = threadIdx.x & 63;
    int n = (b - 32768) * 4 + w;
    const float4* x4 = (const float4*)(x + (size_t)n * D_EMB);
    ushort4* xb4 = (ushort4*)(xb + (size_t)n * D_EMB);
    const float4* r4 = (const float4*)rw;
    float acc[NE];
#pragma unroll
    for (int e = 0; e < NE; ++e) acc[e] = 0.f;
#pragma unroll
    for (int c = 0; c < 4; ++c) {
      float4 xv = x4[c * 64 + lane];
      ushort4 o;
      o.x = f2bf(xv.x); o.y = f2bf(xv.y); o.z = f2bf(xv.z); o.w = f2bf(xv.w);
      xb4[c * 64 + lane] = o;
#pragma unroll
      for (int e = 0; e < NE; ++e) {
        float4 wv = r4[e * 256 + c * 64 + lane];
        acc[e] += xv.x * wv.x + xv.y * wv.y + xv.z * wv.z + xv.w * wv.w;
      }
    }
#pragma unroll
    for (int e = 0; e < NE; ++e) {
      float v = acc[e];
#pragma unroll
      for (int off = 32; off >= 1; off >>= 1) v += __shfl_xor(v, off);
      acc[e] = v;
    }
    if (lane == 0) {
      int e0 = 0; float v0 = acc[0];
#pragma unroll
      for (int e = 1; e < NE; ++e) if (acc[e] > v0) { v0 = acc[e]; e0 = e; }
      int e1 = -1; float v1 = -1e30f;
#pragma unroll
      for (int e = 0; e < NE; ++e) if (e != e0 && acc[e] > v1) { v1 = acc[e]; e1 = e; }
      float p1 = expf(v1 - v0);          // p(top2)/p(top1)
      float g0 = 1.f / (1.f + p1);
      float g1 = p1 * g0;
      ti[2 * n] = e0; ti[2 * n + 1] = e1;
      tg[2 * n] = g0; tg[2 * n + 1] = g1;
    }
    return;
  }
  __shared__ ushort t[32][33];
  int rl = threadIdx.x >> 3, q = threadIdx.x & 7;
  if (b < 16384) {                        // ---- W1 transpose ----
    int bx = b & 511, by = b >> 9;
    const int C = NE * D_FFN;
    float4 v = *(const float4*)&w1[(size_t)(by * 32 + rl) * C + bx * 32 + q * 4];
    t[rl][q * 4 + 0] = f2bf(v.x);
    t[rl][q * 4 + 1] = f2bf(v.y);
    t[rl][q * 4 + 2] = f2bf(v.z);
    t[rl][q * 4 + 3] = f2bf(v.w);
    __syncthreads();
    ushort4 o;
    o.x = t[q * 4 + 0][rl];
    o.y = t[q * 4 + 1][rl];
    o.z = t[q * 4 + 2][rl];
    o.w = t[q * 4 + 3][rl];
    *(ushort4*)&w1t[(size_t)(bx * 32 + rl) * D_EMB + by * 32 + q * 4] = o;
  } else {                                // ---- W2 per-expert transpose ----
    int b2 = b - 16384;
    int bx = b2 & 31, by = b2 >> 5;
    float4 v = *(const float4*)&w2[(size_t)(by * 32 + rl) * D_EMB + bx * 32 + q * 4];
    t[rl][q * 4 + 0] = f2bf(v.x);
    t[rl][q * 4 + 1] = f2bf(v.y);
    t[rl][q * 4 + 2] = f2bf(v.z);
    t[rl][q * 4 + 3] = f2bf(v.w);
    __syncthreads();
    int e = by >> 6;
    int f0 = (by & 63) * 32;
    size_t eoff = (size_t)e * (D_EMB * D_FFN);
    ushort4 o;
    o.x = t[q * 4 + 0][rl];
    o.y = t[q * 4 + 1][rl];
    o.z = t[q * 4 + 2][rl];
    o.w = t[q * 4 + 3][rl];
    *(ushort4*)&w2te[eoff + (size_t)(bx * 32 + rl) * D_FFN + f0 + q * 4] = o;
  }
}

// ---- counts: LDS-aggregated histogram, 8 global atomics per block ----------
__global__ __launch_bounds__(256) void hist_k(const int* __restrict__ ti,
                                              int* __restrict__ counts) {
  __shared__ int lc[NE];
  if (threadIdx.x < NE) lc[threadIdx.x] = 0;
  __syncthreads();
  int s = blockIdx.x * 512 + threadIdx.x;
  atomicAdd(&lc[ti[s]], 1);
  atomicAdd(&lc[ti[s + 256]], 1);
  __syncthreads();
  if (threadIdx.x < NE) atomicAdd(&counts[threadIdx.x], lc[threadIdx.x]);
}

__global__ void prefix_k(const int* __restrict__ counts, int* __restrict__ bases,
                         int* __restrict__ cursor) {
  if (threadIdx.x == 0) {
    int s = 0;
    for (int e = 0; e < NE; ++e) { bases[e] = s; cursor[e] = s; s += counts[e]; }
  }
}

// ---- scatter: two-phase; tokS[pos] = s (= token*2 + slot-index) ------------
__global__ __launch_bounds__(256) void scatter_k(const int* __restrict__ ti,
                                                 const float* __restrict__ tg,
                                                 int* __restrict__ cursor,
                                                 int* __restrict__ tokS,
                                                 float* __restrict__ gate) {
  __shared__ int lc[NE], lb[NE];
  if (threadIdx.x < NE) lc[threadIdx.x] = 0;
  __syncthreads();
  int s = blockIdx.x * 256 + threadIdx.x;
  int e = ti[s];
  float g = tg[s];
  int loc = atomicAdd(&lc[e], 1);
  __syncthreads();
  if (threadIdx.x < NE) lb[threadIdx.x] = atomicAdd(&cursor[threadIdx.x], lc[threadIdx.x]);
  __syncthreads();
  int pos = lb[e] + loc;
  tokS[pos] = s;
  gate[pos] = g;
}

// ===== 128x128 / BK=32 grouped GEMM, dbuf + counted vmcnt(4) [proven R12] ===
// Slot swizzle phys = slot ^ ((row>>1)&3), both-sides via pre-swizzled global
// col; measured 0 bank conflicts. STAGE(t+1) issues BEFORE waiting; VW(4)
// drains only tile t's 4 loads. Raw s_barriers (no implicit vmcnt(0) drain).
// Epilogue: output tile staged through LDS (reusing Bl, per-wave 16x72 strip)
// -> b128 readback -> coalesced 16B global stores.

#define STG(BUF)                                                           \
  { _Pragma("unroll") for (int j_ = 0; j_ < 2; ++j_) {                     \
      gll16(aptr[j_], &Al[BUF][ldso[j_]]);                                 \
      gll16(bptr[j_], &Bl[BUF][ldso[j_]]);                                 \
      aptr[j_] += BK; bptr[j_] += BK;                                      \
    } }

#define CMP(BUF)                                                           \
  { short8 a[4], b[4];                                                     \
    _Pragma("unroll") for (int i_ = 0; i_ < 4; ++i_)                       \
      a[i_] = *(const short8*)&Al[BUF][arow + i_ * 16 * BK];               \
    _Pragma("unroll") for (int j_ = 0; j_ < 4; ++j_)                       \
      b[j_] = *(const short8*)&Bl[BUF][brow + j_ * 16 * BK];               \
    _Pragma("unroll") for (int i_ = 0; i_ < 4; ++i_)                       \
      _Pragma("unroll") for (int j_ = 0; j_ < 4; ++j_)                     \
        acc[i_][j_] = __builtin_amdgcn_mfma_f32_16x16x32_bf16(a[i_], b[j_], acc[i_][j_], 0, 0, 0); \
  }

#define KLOOP(NT)                                                          \
  STG(0);                                                                  \
  for (int ks = 0; ks < (NT) - 2; ks += 2) {                               \
    STG(1); VW(4); BAR(); CMP(0); BAR();                                   \
    STG(0); VW(4); BAR(); CMP(1); BAR();                                   \
  }                                                                        \
  STG(1); VW(4); BAR(); CMP(0); BAR();                                     \
  VW(0); BAR(); CMP(1);

// ---------------- grouped GEMM1: h = gelu(x @ W1_e), gathered rows ----------
__global__ __launch_bounds__(256) void gemm1_k(const ushort* __restrict__ xb,
                                               const ushort* __restrict__ w1t,
                                               const int* __restrict__ counts,
                                               const int* __restrict__ bases,
                                               const int* __restrict__ tokS,
                                               ushort* __restrict__ h) {
  int bid = (int)blockIdx.x;
  bid = (bid & 7) * 512 + (bid >> 3);   // XCD-contiguous: 1 expert/XCD
  int e = bid >> 9;                     // 32 mt * 16 nt per expert
  int rem = bid & 511;
  int mt = rem >> 4, nt = rem & 15;
  int count = counts[e];
  if (mt * BM >= count) return;
  int base = bases[e];

  __shared__ ushort Al[2][BM * BK];
  __shared__ ushort Bl[2][BN * BK];

  int tid = threadIdx.x;
  int w = tid >> 6, lane = tid & 63;

  const int ssw = (((lane & 3) ^ ((lane >> 3) & 3))) * 8;

  const ushort* aptr[2]; const ushort* bptr[2];
  int ldso[2];
#pragma unroll
  for (int j = 0; j < 2; ++j) {
    int rl = w * 32 + j * 16 + (lane >> 2);
    int pr = min(base + mt * BM + rl, base + count - 1);
    int t = tokS[pr] >> 1;
    aptr[j] = xb + (size_t)t * D_EMB + ssw;
    int c = e * D_FFN + nt * BN + rl;
    bptr[j] = w1t + (size_t)c * D_EMB + ssw;
    ldso[j] = (w * 32 + j * 16) * BK;
  }

  f32x4 zero = {0.f, 0.f, 0.f, 0.f};
  f32x4 acc[4][4];
#pragma unroll
  for (int i = 0; i < 4; ++i)
#pragma unroll
    for (int j = 0; j < 4; ++j) acc[i][j] = zero;

  int wm = w >> 1, wn = w & 1;
  const int rsw = ((lane >> 4) ^ (((lane & 15) >> 1) & 3)) * 8;
  const int arow = (wm * 64 + (lane & 15)) * BK + rsw;
  const int brow = (wn * 64 + (lane & 15)) * BK + rsw;

  KLOOP(D_EMB / BK);   // 32 tiles

  // ---- LDS-staged vectorized epilogue ----
  __syncthreads();                      // all waves done reading Al/Bl
  ushort* ep = &Bl[0][0] + w * (16 * 72);
  int r0 = mt * BM + wm * 64, c0 = nt * BN + wn * 64;
  const int l15 = lane & 15;
#pragma unroll
  for (int i = 0; i < 4; ++i) {
#pragma unroll
    for (int j = 0; j < 4; ++j)
#pragma unroll
      for (int q = 0; q < 4; ++q)
        ep[((lane >> 4) * 4 + q) * 72 + j * 16 + l15] = f2bf(gelu_f(acc[i][j][q]));
    LKW();                              // intra-wave write->read (DS in-order)
#pragma unroll
    for (int rd = 0; rd < 2; ++rd) {
      int sr = (lane >> 3) + rd * 8;
      int sc = (lane & 7) * 8;
      short8 v = *(const short8*)&ep[sr * 72 + sc];
      int row = r0 + i * 16 + sr;
      if (row < count)
        *(short8*)&h[(size_t)(base + row) * D_FFN + c0 + sc] = v;
    }
    LKW();                              // reads done before next-iter writes
  }
}

// -- grouped GEMM2: y2[tok*2+k] = gate * (h @ W2_e), token-major, bf16 -------
__global__ __launch_bounds__(256) void gemm2_k(const ushort* __restrict__ h,
                                               const ushort* __restrict__ w2te,
                                               const int* __restrict__ counts,
                                               const int* __restrict__ bases,
                                               const int* __restrict__ tokS,
                                               const float* __restrict__ gate,
                                               ushort* __restrict__ y2) {
  int bid = (int)blockIdx.x;
  bid = (bid & 7) * 256 + (bid >> 3);   // XCD-contiguous: 1 expert/XCD
  int e = bid >> 8;                     // 32 mt * 8 nt per expert
  int rem = bid & 255;
  int mt = rem >> 3, nt = rem & 7;
  int count = counts[e];
  if (mt * BM >= count) return;
  int base = bases[e];

  __shared__ ushort Al[2][BM * BK];
  __shared__ ushort Bl[2][BN * BK];

  int tid = threadIdx.x;
  int w = tid >> 6, lane = tid & 63;

  const int ssw = (((lane & 3) ^ ((lane >> 3) & 3))) * 8;

  const ushort* aptr[2]; const ushort* bptr[2];
  int ldso[2];
#pragma unroll
  for (int j = 0; j < 2; ++j) {
    int rl = w * 32 + j * 16 + (lane >> 2);
    int pr = min(base + mt * BM + rl, base + count - 1);
    aptr[j] = h + (size_t)pr * D_FFN + ssw;
    int d = nt * BN + rl;               // output column (embedding dim)
    bptr[j] = w2te + (size_t)e * (D_EMB * D_FFN) + (size_t)d * D_FFN + ssw;
    ldso[j] = (w * 32 + j * 16) * BK;
  }

  f32x4 zero = {0.f, 0.f, 0.f, 0.f};
  f32x4 acc[4][4];
#pragma unroll
  for (int i = 0; i < 4; ++i)
#pragma unroll
    for (int j = 0; j < 4; ++j) acc[i][j] = zero;

  int wm = w >> 1, wn = w & 1;
  const int rsw = ((lane >> 4) ^ (((lane & 15) >> 1) & 3)) * 8;
  const int arow = (wm * 64 + (lane & 15)) * BK + rsw;
  const int brow = (wn * 64 + (lane & 15)) * BK + rsw;

  KLOOP(D_FFN / BK);   // 64 tiles

  // ---- LDS-staged vectorized epilogue (gate applied pre-stage) ----
  __syncthreads();
  ushort* ep = &Bl[0][0] + w * (16 * 72);
  int r0 = mt * BM + wm * 64, c0 = nt * BN + wn * 64;
  const int l15 = lane & 15;
#pragma unroll
  for (int i = 0; i < 4; ++i) {
#pragma unroll
    for (int q = 0; q < 4; ++q) {
      int row = r0 + i * 16 + (lane >> 4) * 4 + q;
      int pr = min(base + row, base + count - 1);   // clamp: no OOB gate read
      float g = gate[pr];
#pragma unroll
      for (int j = 0; j < 4; ++j)
        ep[((lane >> 4) * 4 + q) * 72 + j * 16 + l15] = f2bf(g * acc[i][j][q]);
    }
    LKW();
#pragma unroll
    for (int rd = 0; rd < 2; ++rd) {
      int sr = (lane >> 3) + rd * 8;
      int sc = (lane & 7) * 8;
      short8 v = *(const short8*)&ep[sr * 72 + sc];
      int row = r0 + i * 16 + sr;
      if (row < count) {
        int pr = base + row;
        *(short8*)&y2[(size_t)tokS[pr] * D_EMB + c0 + sc] = v;  // token-major
      }
    }
    LKW();
  }
}

// ---- combine: out[n] = y2[2n] + y2[2n+1] (streaming, gates pre-applied) ----
__global__ __launch_bounds__(256) void combine_k(const ushort* __restrict__ y2,
                                                 float* __restrict__ out) {
  int n = blockIdx.x;
  const ushort4* r0 = (const ushort4*)(y2 + (size_t)(2 * n) * D_EMB);
  const ushort4* r1 = (const ushort4*)(y2 + (size_t)(2 * n + 1) * D_EMB);
  float4* o = (float4*)(out + (size_t)n * D_EMB);
  int i = threadIdx.x;
  ushort4 a = r0[i], b = r1[i];
  float4 v;
  v.x = bf2f(a.x) + bf2f(b.x);
  v.y = bf2f(a.y) + bf2f(b.y);
  v.z = bf2f(a.z) + bf2f(b.z);
  v.w = bf2f(a.w) + bf2f(b.w);
  o[i] = v;
}

extern "C" void kernel_launch(void* const* d_in, const int* in_sizes, int n_in,
                              void* d_out, int out_size, void* d_ws, size_t ws_size,
                              hipStream_t stream) {
  const float* x  = (const float*)d_in[0];
  const float* rw = (const float*)d_in[1];
  const float* w1 = (const float*)d_in[2];
  const float* w2 = (const float*)d_in[3];
  float* out = (float*)d_out;

  char* ws = (char*)d_ws;
  size_t off = 0;
  auto alloc = [&](size_t bytes) {
    void* p = ws + off;
    off = (off + bytes + 255) & ~(size_t)255;
    return p;
  };
  int*    counts = (int*)alloc(32);
  int*    bases  = (int*)alloc(32);
  int*    cursor = (int*)alloc(32);
  int*    ti     = (int*)alloc((size_t)N_TOK * 2 * sizeof(int));
  float*  tg     = (float*)alloc((size_t)N_TOK * 2 * sizeof(float));
  int*    tokS   = (int*)alloc((size_t)N_TOK * 2 * sizeof(int));
  float*  gate   = (float*)alloc((size_t)N_TOK * 2 * sizeof(float));
  ushort* xb     = (ushort*)alloc((size_t)N_TOK * D_EMB * 2);
  ushort* w1t    = (ushort*)alloc((size_t)D_EMB * NE * D_FFN * 2);
  ushort* w2te   = (ushort*)alloc((size_t)D_EMB * NE * D_FFN * 2);
  ushort* hbuf   = (ushort*)alloc((size_t)N_TOK * 2 * D_FFN * 2);
  ushort* ybuf   = (ushort*)alloc((size_t)N_TOK * 2 * D_EMB * 2);
  (void)ws_size; (void)in_sizes; (void)n_in; (void)out_size;

  prep_k<<<34816, 256, 0, stream>>>(w1, w2, x, rw, w1t, w2te, xb, ti, tg, counts);
  hist_k<<<N_TOK * 2 / 512, 256, 0, stream>>>(ti, counts);
  prefix_k<<<1, 64, 0, stream>>>(counts, bases, cursor);
  scatter_k<<<N_TOK * 2 / 256, 256, 0, stream>>>(ti, tg, cursor, tokS, gate);
  gemm1_k<<<NE * 32 * 16, 256, 0, stream>>>(xb, w1t, counts, bases, tokS, hbuf);
  gemm2_k<<<NE * 32 * 8, 256, 0, stream>>>(hbuf, w2te, counts, bases, tokS, gate, ybuf);
  combine_k<<<N_TOK, 256, 0, stream>>>(ybuf, out);
}

// Round 15
// 270.226 us; speedup vs baseline: 1.1148x; 1.0362x over previous
//
#include <hip/hip_runtime.h>
#include <hip/hip_bf16.h>
#include <cstdint>
#include <cstddef>

#define NE 8
#define N_TOK 8192
#define D_EMB 1024
#define D_FFN 2048

#define BM 128
#define BN 128
#define BK 32

typedef __attribute__((ext_vector_type(8))) short short8;
typedef __attribute__((ext_vector_type(4))) float f32x4;

__device__ __forceinline__ unsigned short f2bf(float f) {
  union { float f; unsigned int u; } c; c.f = f;
  unsigned int u = c.u;
  unsigned int r = u + 0x7FFFu + ((u >> 16) & 1u);
  return (unsigned short)(r >> 16);
}

__device__ __forceinline__ float bf2f(unsigned short u) {
  union { unsigned int u; float f; } c; c.u = ((unsigned int)u) << 16;
  return c.f;
}

// gelu, tanh-form as sigmoid: x*sig(2c(x+0.044715x^3)); |delta| <= 3e-3 on h,
// ~1.4e-3 after W2 diffusion. ~8 VALU ops vs erff's ~25.
__device__ __forceinline__ float gelu_f(float x) {
  float u = x * x * x * 0.044715f + x;
  float t = __expf(-1.5957691216057308f * u);
  return x * __builtin_amdgcn_rcpf(1.f + t);
}

__device__ __forceinline__ void gll16(const void* g, void* l) {
  __builtin_amdgcn_global_load_lds((const __attribute__((address_space(1))) void*)g,
                                   (__attribute__((address_space(3))) void*)l, 16, 0, 0);
}

#define SB() __builtin_amdgcn_sched_barrier(0)
#define VW(N) { asm volatile("s_waitcnt vmcnt(" #N ")" ::: "memory"); SB(); }
#define BAR() { SB(); __builtin_amdgcn_s_barrier(); SB(); }
#define LKW() { asm volatile("s_waitcnt lgkmcnt(0)" ::: "memory"); SB(); }

// ---- router: fp32 logits, top-2 + renorm gates; fused x->bf16 convert ------
// Block 0 also zeroes counts (hist runs in a LATER launch -> no race; same-
// stream kernels serialize). Drops the standalone memset launch.
__global__ __launch_bounds__(256) void router_k(const float* __restrict__ x,
                                                const float* __restrict__ rw,
                                                int* __restrict__ ti,
                                                float* __restrict__ tg,
                                                ushort* __restrict__ xb,
                                                int* __restrict__ counts) {
  if (blockIdx.x == 0 && threadIdx.x < NE) counts[threadIdx.x] = 0;
  int w = threadIdx.x >> 6, lane = threadIdx.x & 63;
  int n = blockIdx.x * 4 + w;
  const float4* x4 = (const float4*)(x + (size_t)n * D_EMB);
  ushort4* xb4 = (ushort4*)(xb + (size_t)n * D_EMB);
  const float4* r4 = (const float4*)rw;
  float acc[NE];
#pragma unroll
  for (int e = 0; e < NE; ++e) acc[e] = 0.f;
#pragma unroll
  for (int c = 0; c < 4; ++c) {
    float4 xv = x4[c * 64 + lane];
    ushort4 o;
    o.x = f2bf(xv.x); o.y = f2bf(xv.y); o.z = f2bf(xv.z); o.w = f2bf(xv.w);
    xb4[c * 64 + lane] = o;
#pragma unroll
    for (int e = 0; e < NE; ++e) {
      float4 wv = r4[e * 256 + c * 64 + lane];
      acc[e] += xv.x * wv.x + xv.y * wv.y + xv.z * wv.z + xv.w * wv.w;
    }
  }
#pragma unroll
  for (int e = 0; e < NE; ++e) {
    float v = acc[e];
#pragma unroll
    for (int off = 32; off >= 1; off >>= 1) v += __shfl_xor(v, off);
    acc[e] = v;
  }
  if (lane == 0) {
    int e0 = 0; float v0 = acc[0];
#pragma unroll
    for (int e = 1; e < NE; ++e) if (acc[e] > v0) { v0 = acc[e]; e0 = e; }
    int e1 = -1; float v1 = -1e30f;
#pragma unroll
    for (int e = 0; e < NE; ++e) if (e != e0 && acc[e] > v1) { v1 = acc[e]; e1 = e; }
    float p1 = expf(v1 - v0);          // p(top2)/p(top1)
    float g0 = 1.f / (1.f + p1);
    float g1 = p1 * g0;
    ti[2 * n] = e0; ti[2 * n + 1] = e1;
    tg[2 * n] = g0; tg[2 * n + 1] = g1;
  }
}

// ---- prep: fused {W1-transpose, W2-per-expert-transpose, hist} -------------
// Grid partition:
//   [0, 16384)        : W1 [D_EMB][NE*D_FFN] fp32 -> w1t [NE*D_FFN][D_EMB] bf16
//   [16384, 32768)    : W2 [NE*D_FFN][D_EMB] fp32 -> w2te [NE][D_EMB][D_FFN] bf16
//   [32768, 32800)    : hist (LDS-aggregated, 8 global atomics per block)
__global__ __launch_bounds__(256) void prep_k(const float* __restrict__ w1,
                                              const float* __restrict__ w2,
                                              const int* __restrict__ ti,
                                              ushort* __restrict__ w1t,
                                              ushort* __restrict__ w2te,
                                              int* __restrict__ counts) {
  int b = blockIdx.x;
  if (b >= 32768) {                       // ---- hist ----
    __shared__ int lc[NE];
    if (threadIdx.x < NE) lc[threadIdx.x] = 0;
    __syncthreads();
    int s = (b - 32768) * 512 + threadIdx.x;
    atomicAdd(&lc[ti[s]], 1);
    atomicAdd(&lc[ti[s + 256]], 1);
    __syncthreads();
    if (threadIdx.x < NE) atomicAdd(&counts[threadIdx.x], lc[threadIdx.x]);
    return;
  }
  __shared__ ushort t[32][33];
  int rl = threadIdx.x >> 3, q = threadIdx.x & 7;
  if (b < 16384) {                        // ---- W1 transpose ----
    int bx = b & 511, by = b >> 9;
    const int C = NE * D_FFN;
    float4 v = *(const float4*)&w1[(size_t)(by * 32 + rl) * C + bx * 32 + q * 4];
    t[rl][q * 4 + 0] = f2bf(v.x);
    t[rl][q * 4 + 1] = f2bf(v.y);
    t[rl][q * 4 + 2] = f2bf(v.z);
    t[rl][q * 4 + 3] = f2bf(v.w);
    __syncthreads();
    ushort4 o;
    o.x = t[q * 4 + 0][rl];
    o.y = t[q * 4 + 1][rl];
    o.z = t[q * 4 + 2][rl];
    o.w = t[q * 4 + 3][rl];
    *(ushort4*)&w1t[(size_t)(bx * 32 + rl) * D_EMB + by * 32 + q * 4] = o;
  } else {                                // ---- W2 per-expert transpose ----
    int b2 = b - 16384;
    int bx = b2 & 31, by = b2 >> 5;
    float4 v = *(const float4*)&w2[(size_t)(by * 32 + rl) * D_EMB + bx * 32 + q * 4];
    t[rl][q * 4 + 0] = f2bf(v.x);
    t[rl][q * 4 + 1] = f2bf(v.y);
    t[rl][q * 4 + 2] = f2bf(v.z);
    t[rl][q * 4 + 3] = f2bf(v.w);
    __syncthreads();
    int e = by >> 6;
    int f0 = (by & 63) * 32;
    size_t eoff = (size_t)e * (D_EMB * D_FFN);
    ushort4 o;
    o.x = t[q * 4 + 0][rl];
    o.y = t[q * 4 + 1][rl];
    o.z = t[q * 4 + 2][rl];
    o.w = t[q * 4 + 3][rl];
    *(ushort4*)&w2te[eoff + (size_t)(bx * 32 + rl) * D_FFN + f0 + q * 4] = o;
  }
}

__global__ void prefix_k(const int* __restrict__ counts, int* __restrict__ bases,
                         int* __restrict__ cursor) {
  if (threadIdx.x == 0) {
    int s = 0;
    for (int e = 0; e < NE; ++e) { bases[e] = s; cursor[e] = s; s += counts[e]; }
  }
}

// ---- scatter: two-phase; tokS[pos] = s (= token*2 + slot-index) ------------
__global__ __launch_bounds__(256) void scatter_k(const int* __restrict__ ti,
                                                 const float* __restrict__ tg,
                                                 int* __restrict__ cursor,
                                                 int* __restrict__ tokS,
                                                 float* __restrict__ gate) {
  __shared__ int lc[NE], lb[NE];
  if (threadIdx.x < NE) lc[threadIdx.x] = 0;
  __syncthreads();
  int s = blockIdx.x * 256 + threadIdx.x;
  int e = ti[s];
  float g = tg[s];
  int loc = atomicAdd(&lc[e], 1);
  __syncthreads();
  if (threadIdx.x < NE) lb[threadIdx.x] = atomicAdd(&cursor[threadIdx.x], lc[threadIdx.x]);
  __syncthreads();
  int pos = lb[e] + loc;
  tokS[pos] = s;
  gate[pos] = g;
}

// ===== 128x128 / BK=32 grouped GEMM, dbuf + counted vmcnt(4) [proven R12] ===
// Slot swizzle phys = slot ^ ((row>>1)&3), both-sides via pre-swizzled global
// col; measured 0 bank conflicts. STAGE(t+1) issues BEFORE waiting; VW(4)
// drains only tile t's 4 loads. Raw s_barriers (no implicit vmcnt(0) drain).
// Epilogue: output tile staged through LDS (reusing Bl, per-wave 16x72 strip)
// -> b128 readback -> coalesced 16B global stores.

#define STG(BUF)                                                           \
  { _Pragma("unroll") for (int j_ = 0; j_ < 2; ++j_) {                     \
      gll16(aptr[j_], &Al[BUF][ldso[j_]]);                                 \
      gll16(bptr[j_], &Bl[BUF][ldso[j_]]);                                 \
      aptr[j_] += BK; bptr[j_] += BK;                                      \
    } }

#define CMP(BUF)                                                           \
  { short8 a[4], b[4];                                                     \
    _Pragma("unroll") for (int i_ = 0; i_ < 4; ++i_)                       \
      a[i_] = *(const short8*)&Al[BUF][arow + i_ * 16 * BK];               \
    _Pragma("unroll") for (int j_ = 0; j_ < 4; ++j_)                       \
      b[j_] = *(const short8*)&Bl[BUF][brow + j_ * 16 * BK];               \
    _Pragma("unroll") for (int i_ = 0; i_ < 4; ++i_)                       \
      _Pragma("unroll") for (int j_ = 0; j_ < 4; ++j_)                     \
        acc[i_][j_] = __builtin_amdgcn_mfma_f32_16x16x32_bf16(a[i_], b[j_], acc[i_][j_], 0, 0, 0); \
  }

#define KLOOP(NT)                                                          \
  STG(0);                                                                  \
  for (int ks = 0; ks < (NT) - 2; ks += 2) {                               \
    STG(1); VW(4); BAR(); CMP(0); BAR();                                   \
    STG(0); VW(4); BAR(); CMP(1); BAR();                                   \
  }                                                                        \
  STG(1); VW(4); BAR(); CMP(0); BAR();                                     \
  VW(0); BAR(); CMP(1);

// ---------------- grouped GEMM1: h = gelu(x @ W1_e), gathered rows ----------
__global__ __launch_bounds__(256) void gemm1_k(const ushort* __restrict__ xb,
                                               const ushort* __restrict__ w1t,
                                               const int* __restrict__ counts,
                                               const int* __restrict__ bases,
                                               const int* __restrict__ tokS,
                                               ushort* __restrict__ h) {
  int bid = (int)blockIdx.x;
  bid = (bid & 7) * 512 + (bid >> 3);   // XCD-contiguous: 1 expert/XCD
  int e = bid >> 9;                     // 32 mt * 16 nt per expert
  int rem = bid & 511;
  int mt = rem >> 4, nt = rem & 15;
  int count = counts[e];
  if (mt * BM >= count) return;
  int base = bases[e];

  __shared__ ushort Al[2][BM * BK];
  __shared__ ushort Bl[2][BN * BK];

  int tid = threadIdx.x;
  int w = tid >> 6, lane = tid & 63;

  const int ssw = (((lane & 3) ^ ((lane >> 3) & 3))) * 8;

  const ushort* aptr[2]; const ushort* bptr[2];
  int ldso[2];
#pragma unroll
  for (int j = 0; j < 2; ++j) {
    int rl = w * 32 + j * 16 + (lane >> 2);
    int pr = min(base + mt * BM + rl, base + count - 1);
    int t = tokS[pr] >> 1;
    aptr[j] = xb + (size_t)t * D_EMB + ssw;
    int c = e * D_FFN + nt * BN + rl;
    bptr[j] = w1t + (size_t)c * D_EMB + ssw;
    ldso[j] = (w * 32 + j * 16) * BK;
  }

  f32x4 zero = {0.f, 0.f, 0.f, 0.f};
  f32x4 acc[4][4];
#pragma unroll
  for (int i = 0; i < 4; ++i)
#pragma unroll
    for (int j = 0; j < 4; ++j) acc[i][j] = zero;

  int wm = w >> 1, wn = w & 1;
  const int rsw = ((lane >> 4) ^ (((lane & 15) >> 1) & 3)) * 8;
  const int arow = (wm * 64 + (lane & 15)) * BK + rsw;
  const int brow = (wn * 64 + (lane & 15)) * BK + rsw;

  KLOOP(D_EMB / BK);   // 32 tiles

  // ---- LDS-staged vectorized epilogue ----
  __syncthreads();                      // all waves done reading Al/Bl
  ushort* ep = &Bl[0][0] + w * (16 * 72);
  int r0 = mt * BM + wm * 64, c0 = nt * BN + wn * 64;
  const int l15 = lane & 15;
#pragma unroll
  for (int i = 0; i < 4; ++i) {
#pragma unroll
    for (int j = 0; j < 4; ++j)
#pragma unroll
      for (int q = 0; q < 4; ++q)
        ep[((lane >> 4) * 4 + q) * 72 + j * 16 + l15] = f2bf(gelu_f(acc[i][j][q]));
    LKW();                              // intra-wave write->read (DS in-order)
#pragma unroll
    for (int rd = 0; rd < 2; ++rd) {
      int sr = (lane >> 3) + rd * 8;
      int sc = (lane & 7) * 8;
      short8 v = *(const short8*)&ep[sr * 72 + sc];
      int row = r0 + i * 16 + sr;
      if (row < count)
        *(short8*)&h[(size_t)(base + row) * D_FFN + c0 + sc] = v;
    }
    LKW();                              // reads done before next-iter writes
  }
}

// -- grouped GEMM2: y2[tok*2+k] = gate * (h @ W2_e), token-major, bf16 -------
__global__ __launch_bounds__(256) void gemm2_k(const ushort* __restrict__ h,
                                               const ushort* __restrict__ w2te,
                                               const int* __restrict__ counts,
                                               const int* __restrict__ bases,
                                               const int* __restrict__ tokS,
                                               const float* __restrict__ gate,
                                               ushort* __restrict__ y2) {
  int bid = (int)blockIdx.x;
  bid = (bid & 7) * 256 + (bid >> 3);   // XCD-contiguous: 1 expert/XCD
  int e = bid >> 8;                     // 32 mt * 8 nt per expert
  int rem = bid & 255;
  int mt = rem >> 3, nt = rem & 7;
  int count = counts[e];
  if (mt * BM >= count) return;
  int base = bases[e];

  __shared__ ushort Al[2][BM * BK];
  __shared__ ushort Bl[2][BN * BK];

  int tid = threadIdx.x;
  int w = tid >> 6, lane = tid & 63;

  const int ssw = (((lane & 3) ^ ((lane >> 3) & 3))) * 8;

  const ushort* aptr[2]; const ushort* bptr[2];
  int ldso[2];
#pragma unroll
  for (int j = 0; j < 2; ++j) {
    int rl = w * 32 + j * 16 + (lane >> 2);
    int pr = min(base + mt * BM + rl, base + count - 1);
    aptr[j] = h + (size_t)pr * D_FFN + ssw;
    int d = nt * BN + rl;               // output column (embedding dim)
    bptr[j] = w2te + (size_t)e * (D_EMB * D_FFN) + (size_t)d * D_FFN + ssw;
    ldso[j] = (w * 32 + j * 16) * BK;
  }

  f32x4 zero = {0.f, 0.f, 0.f, 0.f};
  f32x4 acc[4][4];
#pragma unroll
  for (int i = 0; i < 4; ++i)
#pragma unroll
    for (int j = 0; j < 4; ++j) acc[i][j] = zero;

  int wm = w >> 1, wn = w & 1;
  const int rsw = ((lane >> 4) ^ (((lane & 15) >> 1) & 3)) * 8;
  const int arow = (wm * 64 + (lane & 15)) * BK + rsw;
  const int brow = (wn * 64 + (lane & 15)) * BK + rsw;

  KLOOP(D_FFN / BK);   // 64 tiles

  // ---- LDS-staged vectorized epilogue (gate applied pre-stage) ----
  __syncthreads();
  ushort* ep = &Bl[0][0] + w * (16 * 72);
  int r0 = mt * BM + wm * 64, c0 = nt * BN + wn * 64;
  const int l15 = lane & 15;
#pragma unroll
  for (int i = 0; i < 4; ++i) {
#pragma unroll
    for (int q = 0; q < 4; ++q) {
      int row = r0 + i * 16 + (lane >> 4) * 4 + q;
      int pr = min(base + row, base + count - 1);   // clamp: no OOB gate read
      float g = gate[pr];
#pragma unroll
      for (int j = 0; j < 4; ++j)
        ep[((lane >> 4) * 4 + q) * 72 + j * 16 + l15] = f2bf(g * acc[i][j][q]);
    }
    LKW();
#pragma unroll
    for (int rd = 0; rd < 2; ++rd) {
      int sr = (lane >> 3) + rd * 8;
      int sc = (lane & 7) * 8;
      short8 v = *(const short8*)&ep[sr * 72 + sc];
      int row = r0 + i * 16 + sr;
      if (row < count) {
        int pr = base + row;
        *(short8*)&y2[(size_t)tokS[pr] * D_EMB + c0 + sc] = v;  // token-major
      }
    }
    LKW();
  }
}

// ---- combine: out[n] = y2[2n] + y2[2n+1] (streaming, gates pre-applied) ----
__global__ __launch_bounds__(256) void combine_k(const ushort* __restrict__ y2,
                                                 float* __restrict__ out) {
  int n = blockIdx.x;
  const ushort4* r0 = (const ushort4*)(y2 + (size_t)(2 * n) * D_EMB);
  const ushort4* r1 = (const ushort4*)(y2 + (size_t)(2 * n + 1) * D_EMB);
  float4* o = (float4*)(out + (size_t)n * D_EMB);
  int i = threadIdx.x;
  ushort4 a = r0[i], b = r1[i];
  float4 v;
  v.x = bf2f(a.x) + bf2f(b.x);
  v.y = bf2f(a.y) + bf2f(b.y);
  v.z = bf2f(a.z) + bf2f(b.z);
  v.w = bf2f(a.w) + bf2f(b.w);
  o[i] = v;
}

extern "C" void kernel_launch(void* const* d_in, const int* in_sizes, int n_in,
                              void* d_out, int out_size, void* d_ws, size_t ws_size,
                              hipStream_t stream) {
  const float* x  = (const float*)d_in[0];
  const float* rw = (const float*)d_in[1];
  const float* w1 = (const float*)d_in[2];
  const float* w2 = (const float*)d_in[3];
  float* out = (float*)d_out;

  char* ws = (char*)d_ws;
  size_t off = 0;
  auto alloc = [&](size_t bytes) {
    void* p = ws + off;
    off = (off + bytes + 255) & ~(size_t)255;
    return p;
  };
  int*    counts = (int*)alloc(32);
  int*    bases  = (int*)alloc(32);
  int*    cursor = (int*)alloc(32);
  int*    ti     = (int*)alloc((size_t)N_TOK * 2 * sizeof(int));
  float*  tg     = (float*)alloc((size_t)N_TOK * 2 * sizeof(float));
  int*    tokS   = (int*)alloc((size_t)N_TOK * 2 * sizeof(int));
  float*  gate   = (float*)alloc((size_t)N_TOK * 2 * sizeof(float));
  ushort* xb     = (ushort*)alloc((size_t)N_TOK * D_EMB * 2);
  ushort* w1t    = (ushort*)alloc((size_t)D_EMB * NE * D_FFN * 2);
  ushort* w2te   = (ushort*)alloc((size_t)D_EMB * NE * D_FFN * 2);
  ushort* hbuf   = (ushort*)alloc((size_t)N_TOK * 2 * D_FFN * 2);
  ushort* ybuf   = (ushort*)alloc((size_t)N_TOK * 2 * D_EMB * 2);
  (void)ws_size; (void)in_sizes; (void)n_in; (void)out_size;

  router_k<<<N_TOK / 4, 256, 0, stream>>>(x, rw, ti, tg, xb, counts);
  prep_k<<<32800, 256, 0, stream>>>(w1, w2, ti, w1t, w2te, counts);
  prefix_k<<<1, 64, 0, stream>>>(counts, bases, cursor);
  scatter_k<<<N_TOK * 2 / 256, 256, 0, stream>>>(ti, tg, cursor, tokS, gate);
  gemm1_k<<<NE * 32 * 16, 256, 0, stream>>>(xb, w1t, counts, bases, tokS, hbuf);
  gemm2_k<<<NE * 32 * 8, 256, 0, stream>>>(hbuf, w2te, counts, bases, tokS, gate, ybuf);
  combine_k<<<N_TOK, 256, 0, stream>>>(ybuf, out);
}